// Round 2
// baseline (172.706 us; speedup 1.0000x reference)
//
#include <hip/hip_runtime.h>

#define BB 4
#define CC 128
#define HH 96
#define WWX 96
#define RED 32
#define HW (HH * WWX)
#define NPIX (BB * HW)
#define PADW 3
#define EPSC 1e-8f

// ---------------- Kernel A: 1x1 reduce conv + per-pixel norm ----------------
// feat stored (pix, 32) so each pixel's feature vector is contiguous (128B).
__global__ __launch_bounds__(64) void reduce_kern(
    const float* __restrict__ x, const float* __restrict__ Wr,
    float* __restrict__ feat, float* __restrict__ norms) {
  int pix = blockIdx.x * 64 + threadIdx.x;
  if (pix >= NPIX) return;
  int b = pix / HW;
  int p = pix - b * HW;
  const float* xp = x + (size_t)b * CC * HW + p;

  float acc[RED];
#pragma unroll
  for (int r = 0; r < RED; ++r) acc[r] = 0.f;

  // c-loop: x load coalesced across lanes; Wr index wave-uniform -> s_load
  for (int c = 0; c < CC; ++c) {
    float xv = xp[(size_t)c * HW];
#pragma unroll
    for (int r = 0; r < RED; ++r) acc[r] = fmaf(Wr[r * CC + c], xv, acc[r]);
  }

  float ss = 0.f;
#pragma unroll
  for (int r = 0; r < RED; ++r) ss = fmaf(acc[r], acc[r], ss);
  norms[pix] = sqrtf(ss);

  float4* fo = (float4*)(feat + (size_t)pix * RED);
#pragma unroll
  for (int r4 = 0; r4 < RED / 4; ++r4)
    fo[r4] = make_float4(acc[4 * r4], acc[4 * r4 + 1], acc[4 * r4 + 2], acc[4 * r4 + 3]);
}

// ------------- Kernel B: fused cosine-attention + 1x1 proj + residual -------
// One thread per pixel. Single pass over 49 neighbors (no softmax max pass:
// |cos sim| <= 1 so exp never overflows). OOB neighbor => sim = 0 exactly
// (zero pad, dot=0, denom=eps) => contributes exp(0)=1 to denominator only.
__global__ __launch_bounds__(64) void corr_kern(
    const float* __restrict__ x, const float* __restrict__ Wp,
    const float* __restrict__ feat, const float* __restrict__ norms,
    float* __restrict__ out) {
  int tx = threadIdx.x & 7, ty = threadIdx.x >> 3;
  int gx = blockIdx.x * 8 + tx;
  int gy = blockIdx.y * 8 + ty;
  int b = blockIdx.z;
  int p = gy * WWX + gx;
  int pix = b * HW + p;

  float f[RED];
  const float4* fc = (const float4*)(feat + (size_t)pix * RED);
#pragma unroll
  for (int r4 = 0; r4 < 8; ++r4) {
    float4 t = fc[r4];
    f[4 * r4] = t.x; f[4 * r4 + 1] = t.y; f[4 * r4 + 2] = t.z; f[4 * r4 + 3] = t.w;
  }
  float nc = norms[pix];

  float corr[RED];
#pragma unroll
  for (int r = 0; r < RED; ++r) corr[r] = 0.f;
  float l = 0.f;

#pragma unroll
  for (int dy = -PADW; dy <= PADW; ++dy) {
    int yy = gy + dy;
    bool rowok = ((unsigned)yy < HH);
#pragma unroll
    for (int dx = -PADW; dx <= PADW; ++dx) {
      int xx = gx + dx;
      if (rowok && ((unsigned)xx < WWX)) {
        int npx = b * HW + yy * WWX + xx;
        const float4* fn = (const float4*)(feat + (size_t)npx * RED);
        float v[RED];
#pragma unroll
        for (int r4 = 0; r4 < 8; ++r4) {
          float4 t = fn[r4];
          v[4 * r4] = t.x; v[4 * r4 + 1] = t.y; v[4 * r4 + 2] = t.z; v[4 * r4 + 3] = t.w;
        }
        float dot = 0.f;
#pragma unroll
        for (int r = 0; r < RED; ++r) dot = fmaf(f[r], v[r], dot);
        float np = norms[npx];
        float denom = fmaxf(nc * np, EPSC);
        float sim = dot / denom;
        float wgt = __expf(sim);
        l += wgt;
#pragma unroll
        for (int r = 0; r < RED; ++r) corr[r] = fmaf(wgt, v[r], corr[r]);
      } else {
        l += 1.f;  // exp(0) for zero-padded (OOB) patch
      }
    }
  }

  float invl = 1.f / l;
#pragma unroll
  for (int r = 0; r < RED; ++r) corr[r] *= invl;

  // 1x1 proj (W_proj uniform-index -> scalar loads) + residual, coalesced.
  const float* xc = x + (size_t)b * CC * HW + p;
  float* oc = out + (size_t)b * CC * HW + p;
  for (int c = 0; c < CC; ++c) {
    float a = xc[(size_t)c * HW];
#pragma unroll
    for (int r = 0; r < RED; ++r) a = fmaf(Wp[c * RED + r], corr[r], a);
    oc[(size_t)c * HW] = a;
  }
}

extern "C" void kernel_launch(void* const* d_in, const int* in_sizes, int n_in,
                              void* d_out, int out_size, void* d_ws, size_t ws_size,
                              hipStream_t stream) {
  const float* x  = (const float*)d_in[0];
  const float* Wr = (const float*)d_in[1];
  const float* Wp = (const float*)d_in[2];
  float* out = (float*)d_out;

  float* feat  = (float*)d_ws;                       // NPIX*32 floats
  float* norms = feat + (size_t)NPIX * RED;          // NPIX floats

  reduce_kern<<<NPIX / 64, 64, 0, stream>>>(x, Wr, feat, norms);

  dim3 g(WWX / 8, HH / 8, BB);
  corr_kern<<<g, 64, 0, stream>>>(x, Wp, feat, norms, out);
}

// Round 5
// 123.593 us; speedup vs baseline: 1.3974x; 1.3974x over previous
//
#include <hip/hip_runtime.h>

#define BB 4
#define CC 128
#define HH 96
#define WWX 96
#define RED 32
#define HW (HH * WWX)
#define NPIX (BB * HW)
#define PADW 3
#define EPSC 1e-8f

// ---------------- Kernel A: 1x1 reduce conv + per-pixel norm ----------------
// 256 threads = 64 pixels x 4 c-groups (32 c each). cg is wave-uniform
// (readfirstlane) so Wr indexing stays scalar (s_load). Partial acc[32]
// reduced via padded LDS (stride 33 -> conflict-free).
__global__ __launch_bounds__(256) void reduce_kern(
    const float* __restrict__ x, const float* __restrict__ Wr,
    float* __restrict__ feat, float* __restrict__ norms) {
  __shared__ float part[3][64][33];
  int lane = threadIdx.x & 63;
  int cg = __builtin_amdgcn_readfirstlane(threadIdx.x >> 6);  // wave-uniform
  int pix = blockIdx.x * 64 + lane;
  int b = pix / HW;
  int p = pix - b * HW;
  const float* xp = x + (size_t)b * CC * HW + p;

  float acc[RED];
#pragma unroll
  for (int r = 0; r < RED; ++r) acc[r] = 0.f;

#pragma unroll 4
  for (int i = 0; i < CC / 4; ++i) {
    int c = cg * (CC / 4) + i;
    float xv = xp[(size_t)c * HW];  // coalesced: 64 consecutive pixels
#pragma unroll
    for (int r = 0; r < RED; ++r) acc[r] = fmaf(Wr[r * CC + c], xv, acc[r]);
  }

  if (cg != 0) {
#pragma unroll
    for (int r = 0; r < RED; ++r) part[cg - 1][lane][r] = acc[r];
  }
  __syncthreads();
  if (cg == 0) {
#pragma unroll
    for (int g = 0; g < 3; ++g)
#pragma unroll
      for (int r = 0; r < RED; ++r) acc[r] += part[g][lane][r];

    float ss = 0.f;
#pragma unroll
    for (int r = 0; r < RED; ++r) ss = fmaf(acc[r], acc[r], ss);
    norms[pix] = sqrtf(ss);

    float4* fo = (float4*)(feat + (size_t)pix * RED);
#pragma unroll
    for (int r4 = 0; r4 < RED / 4; ++r4)
      fo[r4] = make_float4(acc[4 * r4], acc[4 * r4 + 1], acc[4 * r4 + 2], acc[4 * r4 + 3]);
  }
}

// ------------- Kernel B: fused cosine-attention + 1x1 proj + residual -------
// Phase 1 (attention): 256 threads = 64 pixels (2 rows x 32) x 4 r-groups of
// 8 channels. Quad-lane shfl_xor butterfly completes the 32-ch dot. No
// softmax max-pass needed (|cos sim| <= 1). OOB neighbor contributes exactly
// exp(0)=1 to the denominator (zero pad -> sim = 0).
// Phase 2 (proj): remap to 64 pixels x 4 wave-uniform c-groups (Wp -> s_load),
// corr transposed through padded LDS.
__global__ __launch_bounds__(256) void corr_kern(
    const float* __restrict__ x, const float* __restrict__ Wp,
    const float* __restrict__ feat, const float* __restrict__ norms,
    float* __restrict__ out) {
  __shared__ float cbuf[64][33];
  int tid = threadIdx.x;
  int rg = tid & 3;    // r-group: 8 channels each
  int q = tid >> 2;    // pixel in block 0..63
  int px = q & 31, py = q >> 5;
  int gx = blockIdx.x * 32 + px;
  int gy = blockIdx.y * 2 + py;
  int b = blockIdx.z;
  int pix = b * HW + gy * WWX + gx;

  float f[8];
  {
    const float4* fc = (const float4*)(feat + (size_t)pix * RED + rg * 8);
    float4 t0 = fc[0], t1 = fc[1];
    f[0] = t0.x; f[1] = t0.y; f[2] = t0.z; f[3] = t0.w;
    f[4] = t1.x; f[5] = t1.y; f[6] = t1.z; f[7] = t1.w;
  }
  float nc = norms[pix];

  float corr[8];
#pragma unroll
  for (int r = 0; r < 8; ++r) corr[r] = 0.f;
  float l = 0.f;

#pragma unroll
  for (int dy = -PADW; dy <= PADW; ++dy) {
    int yy = gy + dy;
    bool rowok = ((unsigned)yy < HH);
#pragma unroll
    for (int dx = -PADW; dx <= PADW; ++dx) {
      int xx = gx + dx;
      if (rowok && ((unsigned)xx < WWX)) {
        int npx = b * HW + yy * WWX + xx;
        const float4* fn = (const float4*)(feat + (size_t)npx * RED + rg * 8);
        float4 v0 = fn[0], v1 = fn[1];
        float v[8];
        v[0] = v0.x; v[1] = v0.y; v[2] = v0.z; v[3] = v0.w;
        v[4] = v1.x; v[5] = v1.y; v[6] = v1.z; v[7] = v1.w;
        float dot = 0.f;
#pragma unroll
        for (int r = 0; r < 8; ++r) dot = fmaf(f[r], v[r], dot);
        dot += __shfl_xor(dot, 1);
        dot += __shfl_xor(dot, 2);  // full 32-ch dot in all 4 quad lanes
        float np = norms[npx];
        float sim = dot * __builtin_amdgcn_rcpf(fmaxf(nc * np, EPSC));
        float wgt = __expf(sim);
        l += wgt;
#pragma unroll
        for (int r = 0; r < 8; ++r) corr[r] = fmaf(wgt, v[r], corr[r]);
      } else {
        l += 1.f;  // exp(0) for zero-padded OOB patch
      }
    }
  }

  float invl = __builtin_amdgcn_rcpf(l);
#pragma unroll
  for (int r = 0; r < 8; ++r) cbuf[q][rg * 8 + r] = corr[r] * invl;
  __syncthreads();

  // ---- Phase 2: 1x1 proj + residual ----
  int p2 = tid & 63;
  int cg = __builtin_amdgcn_readfirstlane(tid >> 6);  // wave-uniform c-group
  int px2 = p2 & 31, py2 = p2 >> 5;
  int pp = (blockIdx.y * 2 + py2) * WWX + blockIdx.x * 32 + px2;

  float cr[RED];
#pragma unroll
  for (int r = 0; r < RED; ++r) cr[r] = cbuf[p2][r];  // stride-33: conflict-free

  const float* xc = x + (size_t)b * CC * HW + pp;
  float* oc = out + (size_t)b * CC * HW + pp;
#pragma unroll 4
  for (int i = 0; i < CC / 4; ++i) {
    int c = cg * (CC / 4) + i;
    float a = xc[(size_t)c * HW];
#pragma unroll
    for (int r = 0; r < RED; ++r) a = fmaf(Wp[c * RED + r], cr[r], a);
    oc[(size_t)c * HW] = a;
  }
}

extern "C" void kernel_launch(void* const* d_in, const int* in_sizes, int n_in,
                              void* d_out, int out_size, void* d_ws, size_t ws_size,
                              hipStream_t stream) {
  const float* x  = (const float*)d_in[0];
  const float* Wr = (const float*)d_in[1];
  const float* Wp = (const float*)d_in[2];
  float* out = (float*)d_out;

  float* feat  = (float*)d_ws;               // NPIX*32 floats
  float* norms = feat + (size_t)NPIX * RED;  // NPIX floats

  reduce_kern<<<NPIX / 64, 256, 0, stream>>>(x, Wr, feat, norms);

  dim3 g(WWX / 32, HH / 2, BB);
  corr_kern<<<g, 256, 0, stream>>>(x, Wp, feat, norms, out);
}

// Round 7
// 122.272 us; speedup vs baseline: 1.4125x; 1.0108x over previous
//
#include <hip/hip_runtime.h>

#define BB 4
#define CC 128
#define HH 96
#define WWX 96
#define RED 32
#define HW (HH * WWX)
#define NPIX (BB * HW)
#define EPSC 1e-8f

// corr halo tile: 32x2 pixels -> 38x8 halo
#define TX 32
#define TY 2
#define HX 38
#define HY 8
#define NHALO (HX * HY)   // 304
#define PSTRIDE 36        // floats per staged pixel vector (32 + 4 pad -> 2-way-max banks)

// ---------------- Kernel A: 1x1 reduce conv + per-pixel norm ----------------
// 256 threads = 64 pixels x 4 c-groups (32 c each). cg wave-uniform -> Wr
// stays s_load. unroll 8 => 8 outstanding 256B loads/wave => BW-saturated.
__global__ __launch_bounds__(256) void reduce_kern(
    const float* __restrict__ x, const float* __restrict__ Wr,
    float* __restrict__ feat, float* __restrict__ norms) {
  __shared__ float part[3][64][33];
  int lane = threadIdx.x & 63;
  int cg = __builtin_amdgcn_readfirstlane(threadIdx.x >> 6);
  int pix = blockIdx.x * 64 + lane;
  int b = pix / HW;
  int p = pix - b * HW;
  const float* xp = x + (size_t)b * CC * HW + p;

  float acc[RED];
#pragma unroll
  for (int r = 0; r < RED; ++r) acc[r] = 0.f;

#pragma unroll 8
  for (int i = 0; i < CC / 4; ++i) {
    int c = cg * (CC / 4) + i;
    float xv = xp[(size_t)c * HW];  // coalesced 256B across 64 lanes
#pragma unroll
    for (int r = 0; r < RED; ++r) acc[r] = fmaf(Wr[r * CC + c], xv, acc[r]);
  }

  if (cg != 0) {
#pragma unroll
    for (int r = 0; r < RED; ++r) part[cg - 1][lane][r] = acc[r];
  }
  __syncthreads();
  if (cg == 0) {
#pragma unroll
    for (int g = 0; g < 3; ++g)
#pragma unroll
      for (int r = 0; r < RED; ++r) acc[r] += part[g][lane][r];

    float ss = 0.f;
#pragma unroll
    for (int r = 0; r < RED; ++r) ss = fmaf(acc[r], acc[r], ss);
    norms[pix] = sqrtf(ss);

    float4* fo = (float4*)(feat + (size_t)pix * RED);
#pragma unroll
    for (int r4 = 0; r4 < RED / 4; ++r4)
      fo[r4] = make_float4(acc[4 * r4], acc[4 * r4 + 1], acc[4 * r4 + 2], acc[4 * r4 + 3]);
  }
}

// ------------- Kernel B: fused cosine-attention + 1x1 proj + residual -------
// Stage 38x8 halo of feat(+norms) in LDS (zeros for OOB: reproduces zero-pad
// exactly -> dot=0, np=0 -> denom=eps -> sim=0 -> w=1; branch-free).
// Phase 1: 256 thr = 64 px x 4 rg(8ch); quad shfl_xor completes 32-ch dot.
// No softmax max-pass (|cos| <= 1). Phase 2: remap to 64 px x 4 c-groups.
__global__ __launch_bounds__(256) void corr_kern(
    const float* __restrict__ x, const float* __restrict__ Wp,
    const float* __restrict__ feat, const float* __restrict__ norms,
    float* __restrict__ out) {
  __shared__ float fbuf[NHALO * PSTRIDE];  // 43776 B
  __shared__ float nbuf[NHALO];            // 1216 B
  __shared__ float cbuf[64][33];           // 8448 B  (total 53.4 KB -> 3 blk/CU)
  int tid = threadIdx.x;
  int b = blockIdx.z;
  int bx = blockIdx.x * TX, by = blockIdx.y * TY;

  // ---- stage halo feat (float4 granularity, coalesced in-bounds) ----
  for (int s = tid; s < NHALO * 8; s += 256) {
    int px = s >> 3, part = s & 7;
    int hy = px / HX, hx = px - hy * HX;
    int gy = by - 3 + hy, gx = bx - 3 + hx;
    float4 v = make_float4(0.f, 0.f, 0.f, 0.f);
    if ((unsigned)gy < HH && (unsigned)gx < WWX)
      v = *(const float4*)(feat + (size_t)(b * HW + gy * WWX + gx) * RED + part * 4);
    *(float4*)(fbuf + px * PSTRIDE + part * 4) = v;
  }
  for (int n = tid; n < NHALO; n += 256) {
    int hy = n / HX, hx = n - hy * HX;
    int gy = by - 3 + hy, gx = bx - 3 + hx;
    nbuf[n] = ((unsigned)gy < HH && (unsigned)gx < WWX)
                  ? norms[b * HW + gy * WWX + gx] : 0.f;
  }
  __syncthreads();

  // ---- phase 1: attention ----
  int rg = tid & 3;
  int q = tid >> 2;
  int px1 = q & 31, py1 = q >> 5;
  int hidx = (py1 + 3) * HX + (px1 + 3);

  float f[8];
  {
    const float4* fc = (const float4*)(fbuf + hidx * PSTRIDE + rg * 8);
    float4 t0 = fc[0], t1 = fc[1];
    f[0] = t0.x; f[1] = t0.y; f[2] = t0.z; f[3] = t0.w;
    f[4] = t1.x; f[5] = t1.y; f[6] = t1.z; f[7] = t1.w;
  }
  float nc = nbuf[hidx];

  float corr[8];
#pragma unroll
  for (int r = 0; r < 8; ++r) corr[r] = 0.f;
  float l = 0.f;

#pragma unroll
  for (int dy = -3; dy <= 3; ++dy) {
#pragma unroll
    for (int dx = -3; dx <= 3; ++dx) {
      int ho = hidx + dy * HX + dx;
      const float4* fn = (const float4*)(fbuf + ho * PSTRIDE + rg * 8);
      float4 v0 = fn[0], v1 = fn[1];
      float v[8];
      v[0] = v0.x; v[1] = v0.y; v[2] = v0.z; v[3] = v0.w;
      v[4] = v1.x; v[5] = v1.y; v[6] = v1.z; v[7] = v1.w;
      float dot = 0.f;
#pragma unroll
      for (int r = 0; r < 8; ++r) dot = fmaf(f[r], v[r], dot);
      dot += __shfl_xor(dot, 1);
      dot += __shfl_xor(dot, 2);  // full 32-ch dot in all 4 quad lanes
      float np = nbuf[ho];
      float sim = dot * __builtin_amdgcn_rcpf(fmaxf(nc * np, EPSC));
      float wgt = __expf(sim);
      l += wgt;
#pragma unroll
      for (int r = 0; r < 8; ++r) corr[r] = fmaf(wgt, v[r], corr[r]);
    }
  }

  float invl = __builtin_amdgcn_rcpf(l);
#pragma unroll
  for (int r = 0; r < 8; ++r) cbuf[q][rg * 8 + r] = corr[r] * invl;
  __syncthreads();

  // ---- phase 2: 1x1 proj + residual ----
  int p2 = tid & 63;
  int cg = __builtin_amdgcn_readfirstlane(tid >> 6);
  int px2 = p2 & 31, py2 = p2 >> 5;
  int pp = (by + py2) * WWX + bx + px2;

  float cr[RED];
#pragma unroll
  for (int r = 0; r < RED; ++r) cr[r] = cbuf[p2][r];  // stride-33: 2-way max

  const float* xc = x + (size_t)b * CC * HW + pp;
  float* oc = out + (size_t)b * CC * HW + pp;
#pragma unroll 4
  for (int i = 0; i < CC / 4; ++i) {
    int c = cg * (CC / 4) + i;
    float a = xc[(size_t)c * HW];
#pragma unroll
    for (int r = 0; r < RED; ++r) a = fmaf(Wp[c * RED + r], cr[r], a);
    oc[(size_t)c * HW] = a;
  }
}

extern "C" void kernel_launch(void* const* d_in, const int* in_sizes, int n_in,
                              void* d_out, int out_size, void* d_ws, size_t ws_size,
                              hipStream_t stream) {
  const float* x  = (const float*)d_in[0];
  const float* Wr = (const float*)d_in[1];
  const float* Wp = (const float*)d_in[2];
  float* out = (float*)d_out;

  float* feat  = (float*)d_ws;               // NPIX*32 floats
  float* norms = feat + (size_t)NPIX * RED;  // NPIX floats

  reduce_kern<<<NPIX / 64, 256, 0, stream>>>(x, Wr, feat, norms);

  dim3 g(WWX / TX, HH / TY, BB);
  corr_kern<<<g, 256, 0, stream>>>(x, Wp, feat, norms, out);
}